// Round 8
// baseline (359.734 us; speedup 1.0000x reference)
//
#include <hip/hip_runtime.h>
#include <hip/hip_fp16.h>
#include <math.h>

#define N_NODES 50000
#define N_EDGES 800000
#define ETOT (N_EDGES + N_NODES)
#define F 128
#define SCAN_B 256
#define NSCAN ((N_NODES + SCAN_B - 1) / SCAN_B)   // 196
#define BM 128                                     // gemm rows per block
#define LOG2E 1.44269504088896341f

typedef _Float16 h2 __attribute__((ext_vector_type(2)));

// ---------------- CSR build ----------------
// 8 edges per thread: 2x int4 loads + 8 independent atomic chains.

__global__ void k_count(const int* __restrict__ ei, int* __restrict__ counts) {
    int base = (blockIdx.x * 256 + threadIdx.x) * 8;
    if (base < N_EDGES) {
        int4 a = *(const int4*)(ei + N_EDGES + base);
        int4 b = *(const int4*)(ei + N_EDGES + base + 4);
        atomicAdd(&counts[a.x], 1); atomicAdd(&counts[a.y], 1);
        atomicAdd(&counts[a.z], 1); atomicAdd(&counts[a.w], 1);
        atomicAdd(&counts[b.x], 1); atomicAdd(&counts[b.y], 1);
        atomicAdd(&counts[b.z], 1); atomicAdd(&counts[b.w], 1);
    }
}

__global__ void k_scan1(const int* __restrict__ counts, int* __restrict__ indptr,
                        int* __restrict__ bsums) {
    __shared__ int s[SCAN_B];
    int i = blockIdx.x * SCAN_B + threadIdx.x;
    int v = (i < N_NODES) ? (counts[i] + 1) : 0;   // +1 = self-loop
    s[threadIdx.x] = v;
    __syncthreads();
    #pragma unroll
    for (int off = 1; off < SCAN_B; off <<= 1) {
        int t = (threadIdx.x >= off) ? s[threadIdx.x - off] : 0;
        __syncthreads();
        s[threadIdx.x] += t;
        __syncthreads();
    }
    if (i < N_NODES) indptr[i] = s[threadIdx.x] - v;
    if (threadIdx.x == SCAN_B - 1) bsums[blockIdx.x] = s[SCAN_B - 1];
}

__global__ void k_scan2(int* __restrict__ bsums) {
    __shared__ int s[SCAN_B];
    int v = (threadIdx.x < NSCAN) ? bsums[threadIdx.x] : 0;
    s[threadIdx.x] = v;
    __syncthreads();
    #pragma unroll
    for (int off = 1; off < SCAN_B; off <<= 1) {
        int t = (threadIdx.x >= off) ? s[threadIdx.x - off] : 0;
        __syncthreads();
        s[threadIdx.x] += t;
        __syncthreads();
    }
    if (threadIdx.x < NSCAN) bsums[threadIdx.x] = s[threadIdx.x] - v;
}

__global__ void k_scan3_fill(int* __restrict__ indptr, const int* __restrict__ bsums,
                             int* __restrict__ fill, int* __restrict__ srcs) {
    int i = blockIdx.x * SCAN_B + threadIdx.x;
    if (i < N_NODES) {
        int p = indptr[i] + bsums[blockIdx.x];
        indptr[i] = p;
        fill[i] = p + 1;
        srcs[p] = i;            // self-loop edge first
    }
    if (i == 0) indptr[N_NODES] = ETOT;
}

__global__ void k_fill_edges(const int* __restrict__ ei, int* __restrict__ fill,
                             int* __restrict__ srcs) {
    int base = (blockIdx.x * 256 + threadIdx.x) * 8;
    if (base < N_EDGES) {
        int4 sa = *(const int4*)(ei + base);
        int4 sb = *(const int4*)(ei + base + 4);
        int4 da = *(const int4*)(ei + N_EDGES + base);
        int4 db = *(const int4*)(ei + N_EDGES + base + 4);
        int p0 = atomicAdd(&fill[da.x], 1);
        int p1 = atomicAdd(&fill[da.y], 1);
        int p2 = atomicAdd(&fill[da.z], 1);
        int p3 = atomicAdd(&fill[da.w], 1);
        int p4 = atomicAdd(&fill[db.x], 1);
        int p5 = atomicAdd(&fill[db.y], 1);
        int p6 = atomicAdd(&fill[db.z], 1);
        int p7 = atomicAdd(&fill[db.w], 1);
        srcs[p0] = sa.x; srcs[p1] = sa.y; srcs[p2] = sa.z; srcs[p3] = sa.w;
        srcs[p4] = sb.x; srcs[p5] = sb.y; srcs[p6] = sb.z; srcs[p7] = sb.w;
    }
}

// ---------------- GEMM: Cf[N,128]=A@W (fp32) + Ch[N,128] fp16 gather copy ----------------

__global__ __launch_bounds__(256) void k_gemm(const float* __restrict__ A,
                                              const float* __restrict__ W,
                                              float* __restrict__ Cf,
                                              unsigned char* __restrict__ Ch) {
    __shared__ float Ws[F][F];     // 64 KB
    int t = threadIdx.x;
    int r0 = blockIdx.x * BM;

    const float4* W4 = (const float4*)W;
    #pragma unroll
    for (int jj = 0; jj < 16; ++jj) {
        int i = t + jj * 256;
        ((float4*)Ws)[i] = W4[i];
    }
    __syncthreads();

    int w = t >> 6, l = t & 63;
    int cx = (l & 7) | ((w & 1) << 3);    // 0..15
    int ry = (l >> 3) | ((w >> 1) << 3);  // 0..15
    int rbase = r0 + ry * 8;

    const float4* Ap[8];
    #pragma unroll
    for (int i = 0; i < 8; ++i) {
        int gr = rbase + i;
        if (gr >= N_NODES) gr = N_NODES - 1;
        Ap[i] = (const float4*)A + (size_t)gr * 32;
    }

    float acc[8][8];
    #pragma unroll
    for (int i = 0; i < 8; ++i)
        #pragma unroll
        for (int j = 0; j < 8; ++j) acc[i][j] = 0.f;

    #pragma unroll 2
    for (int kk = 0; kk < 32; ++kk) {
        float4 xr[8];
        #pragma unroll
        for (int i = 0; i < 8; ++i) xr[i] = Ap[i][kk];
        #pragma unroll
        for (int kj = 0; kj < 4; ++kj) {
            int k = kk * 4 + kj;
            float4 wa = *(const float4*)&Ws[k][cx * 8];
            float4 wb = *(const float4*)&Ws[k][cx * 8 + 4];
            #pragma unroll
            for (int i = 0; i < 8; ++i) {
                float xv = (kj == 0) ? xr[i].x : (kj == 1) ? xr[i].y
                         : (kj == 2) ? xr[i].z : xr[i].w;
                acc[i][0] += xv * wa.x; acc[i][1] += xv * wa.y;
                acc[i][2] += xv * wa.z; acc[i][3] += xv * wa.w;
                acc[i][4] += xv * wb.x; acc[i][5] += xv * wb.y;
                acc[i][6] += xv * wb.z; acc[i][7] += xv * wb.w;
            }
        }
    }

    #pragma unroll
    for (int i = 0; i < 8; ++i) {
        int row = rbase + i;
        if (row < N_NODES) {
            float4* Co = (float4*)(Cf + (size_t)row * F + cx * 8);
            Co[0] = make_float4(acc[i][0], acc[i][1], acc[i][2], acc[i][3]);
            Co[1] = make_float4(acc[i][4], acc[i][5], acc[i][6], acc[i][7]);
            _Float16 hh[8];
            #pragma unroll
            for (int j = 0; j < 8; ++j) hh[j] = (_Float16)acc[i][j];
            *(uint4*)(Ch + (size_t)row * 256 + cx * 16) = *(const uint4*)hh;
        }
    }
}

// ---------------- fused attention + aggregate ----------------
// One wave per node; EIGHT 8-lane groups each own one edge per step.
// Lane owns ONE head (sl = lane&7): feats sl*16..sl*16+15. Both dots are 8
// fdot2 with NO cross-lane reduce; all per-head scalar math is per-lane with
// zero redundancy (8 distinct heads across the group). 2-deep prefetch
// pipeline: next srcs + next row issued before current compute.
// exp->exp2 (LOG2E folded into al/ri). No max-tracking (alphas O(1)).

__global__ __launch_bounds__(256) void k_attn(
    const unsigned char* __restrict__ xt16,
    const int* __restrict__ indptr, const int* __restrict__ srcs,
    const float* __restrict__ att_l, const float* __restrict__ att_r,
    const float* __restrict__ bias, float* __restrict__ out,
    const float* __restrict__ fcW, const float* __restrict__ fcb, int mode) {

    int wid = threadIdx.x >> 6;
    int lane = threadIdx.x & 63;
    int node = blockIdx.x * 4 + wid;
    if (node >= N_NODES) return;
    int sub = lane >> 3;       // edge slot 0..7
    int sl  = lane & 7;        // head index; feats sl*16..sl*16+15

    // xi (fp16, own head's 16 feats) + ri = LOG2E*(a_r.x_i) for head sl
    const uint4* xrow = (const uint4*)(xt16 + (size_t)node * 256 + sl * 32);
    uint4 xa = xrow[0], xb = xrow[1];
    h2 xi_h2[8];
    xi_h2[0] = __builtin_bit_cast(h2, xa.x); xi_h2[1] = __builtin_bit_cast(h2, xa.y);
    xi_h2[2] = __builtin_bit_cast(h2, xa.z); xi_h2[3] = __builtin_bit_cast(h2, xa.w);
    xi_h2[4] = __builtin_bit_cast(h2, xb.x); xi_h2[5] = __builtin_bit_cast(h2, xb.y);
    xi_h2[6] = __builtin_bit_cast(h2, xb.z); xi_h2[7] = __builtin_bit_cast(h2, xb.w);

    const float4* arp = (const float4*)(att_r + sl * 16);
    const float4* alp = (const float4*)(att_l + sl * 16);
    float ri = 0.f;
    h2 al_h2[8];
    #pragma unroll
    for (int q = 0; q < 4; ++q) {
        float4 ar = arp[q];
        float4 al = alp[q];
        ri += (float)xi_h2[2*q].x * ar.x + (float)xi_h2[2*q].y * ar.y
            + (float)xi_h2[2*q+1].x * ar.z + (float)xi_h2[2*q+1].y * ar.w;
        al_h2[2*q]   = h2{(_Float16)(al.x * LOG2E), (_Float16)(al.y * LOG2E)};
        al_h2[2*q+1] = h2{(_Float16)(al.z * LOG2E), (_Float16)(al.w * LOG2E)};
    }
    ri *= LOG2E;

    float d = 0.f;
    float o[16];
    #pragma unroll
    for (int k = 0; k < 16; ++k) o[k] = 0.f;

    int beg = indptr[node], end = indptr[node + 1];
    int nstep = (end - beg + 7) >> 3;

    // pipeline prologue: current row + next srcs
    int idx = beg + sub;
    bool v0 = idx < end;
    int j0 = srcs[v0 ? idx : beg];
    const uint4* rp0 = (const uint4*)(xt16 + (size_t)j0 * 256 + sl * 32);
    uint4 ra0 = rp0[0], rb0 = rp0[1];
    int idx1 = idx + 8;
    bool v1 = idx1 < end;
    int j1 = srcs[v1 ? idx1 : beg];

    for (int s = 0; s < nstep; ++s) {
        // issue next row load + next-next srcs load (both overlap compute below)
        const uint4* rp1 = (const uint4*)(xt16 + (size_t)j1 * 256 + sl * 32);
        uint4 ra1 = rp1[0], rb1 = rp1[1];
        int idx2 = idx1 + 8;
        bool v2 = idx2 < end;
        int j2 = srcs[v2 ? idx2 : beg];

        // compute on current row (ra0, rb0, v0)
        h2 xj[8];
        xj[0] = __builtin_bit_cast(h2, ra0.x); xj[1] = __builtin_bit_cast(h2, ra0.y);
        xj[2] = __builtin_bit_cast(h2, ra0.z); xj[3] = __builtin_bit_cast(h2, ra0.w);
        xj[4] = __builtin_bit_cast(h2, rb0.x); xj[5] = __builtin_bit_cast(h2, rb0.y);
        xj[6] = __builtin_bit_cast(h2, rb0.z); xj[7] = __builtin_bit_cast(h2, rb0.w);

        float lg = 0.f, lj = 0.f;
        #pragma unroll
        for (int k = 0; k < 8; ++k) {
            lg = __builtin_amdgcn_fdot2(xi_h2[k], xj[k], lg, false);
            lj = __builtin_amdgcn_fdot2(al_h2[k], xj[k], lj, false);
        }
        float sg = __builtin_amdgcn_rcpf(1.f + __builtin_amdgcn_exp2f(-lg * LOG2E));
        float a = (lj + ri) * sg;
        a = fmaxf(a, 0.f) + 0.2f * fminf(a, 0.f);  // leaky relu (log2-scaled)
        a = v0 ? a : -1e30f;
        float e = __builtin_amdgcn_exp2f(a);
        d += e;
        #pragma unroll
        for (int k = 0; k < 8; ++k) {
            o[2*k]   += e * (float)xj[k].x;
            o[2*k+1] += e * (float)xj[k].y;
        }

        // rotate pipeline
        ra0 = ra1; rb0 = rb1; v0 = v1; v1 = v2; j1 = j2; idx1 = idx2;
    }

    // combine the eight 8-lane groups (after this, lane holds full head-sl state)
    d += __shfl_xor(d, 8);
    d += __shfl_xor(d, 16);
    d += __shfl_xor(d, 32);
    #pragma unroll
    for (int k = 0; k < 16; ++k) {
        o[k] += __shfl_xor(o[k], 8);
        o[k] += __shfl_xor(o[k], 16);
        o[k] += __shfl_xor(o[k], 32);
    }

    float inv = __builtin_amdgcn_rcpf(d + 1e-16f);
    const float4* bbp = (const float4*)(bias + sl * 16);
    float g[16];
    #pragma unroll
    for (int q = 0; q < 4; ++q) {
        float4 b4 = bbp[q];
        float bq[4] = {b4.x, b4.y, b4.z, b4.w};
        #pragma unroll
        for (int r = 0; r < 4; ++r) {
            float v = o[q*4 + r] * inv + bq[r];
            g[q*4 + r] = 0.5f * v * (1.f + erff(v * 0.70710678118654752f));
        }
    }

    if (mode == 0) {
        if (sub == 0) {
            float4* Co = (float4*)(out + (size_t)node * F + sl * 16);
            Co[0] = make_float4(g[0], g[1], g[2], g[3]);
            Co[1] = make_float4(g[4], g[5], g[6], g[7]);
            Co[2] = make_float4(g[8], g[9], g[10], g[11]);
            Co[3] = make_float4(g[12], g[13], g[14], g[15]);
        }
    } else {
        const float4* fwp = (const float4*)(fcW + sl * 16);
        float p = 0.f;
        #pragma unroll
        for (int q = 0; q < 4; ++q) {
            float4 f4 = fwp[q];
            p += g[q*4]*f4.x + g[q*4+1]*f4.y + g[q*4+2]*f4.z + g[q*4+3]*f4.w;
        }
        p += __shfl_xor(p, 1);
        p += __shfl_xor(p, 2);
        p += __shfl_xor(p, 4);
        if (lane == 0) out[node] = p + fcb[0];
    }
}

// ---------------- launch ----------------

extern "C" void kernel_launch(void* const* d_in, const int* in_sizes, int n_in,
                              void* d_out, int out_size, void* d_ws, size_t ws_size,
                              hipStream_t stream) {
    const float* x     = (const float*)d_in[0];
    const float* W1    = (const float*)d_in[1];
    const float* b1    = (const float*)d_in[2];
    const float* attl1 = (const float*)d_in[3];
    const float* attr1 = (const float*)d_in[4];
    const float* W2    = (const float*)d_in[5];
    const float* b2    = (const float*)d_in[6];
    const float* attl2 = (const float*)d_in[7];
    const float* attr2 = (const float*)d_in[8];
    const float* fcW   = (const float*)d_in[9];
    const float* fcb   = (const float*)d_in[10];
    const int*   ei    = (const int*)d_in[11];
    float* outp = (float*)d_out;

    // workspace (~68 MB): xtf[N][128] f32, h1[N][128] f32, xt16[N][256B], CSR ints
    float* xtf = (float*)d_ws;
    float* h1  = xtf + (size_t)N_NODES * F;
    unsigned char* xt16 = (unsigned char*)(h1 + (size_t)N_NODES * F);
    int* indptr = (int*)(xt16 + (size_t)N_NODES * 256);
    int* fill   = indptr + (N_NODES + 1);
    int* srcs   = fill + N_NODES;
    int* bsums  = srcs + ETOT;
    int* counts = fill;   // aliased: counts dead after scan1, fill written in scan3_fill

    int nb_e8 = (N_EDGES / 8 + 255) / 256;   // 391 (N_EDGES divisible by 8)

    hipMemsetAsync(counts, 0, N_NODES * sizeof(int), stream);
    k_count<<<nb_e8, 256, 0, stream>>>(ei, counts);
    k_scan1<<<NSCAN, SCAN_B, 0, stream>>>(counts, indptr, bsums);
    k_scan2<<<1, SCAN_B, 0, stream>>>(bsums);
    k_scan3_fill<<<NSCAN, SCAN_B, 0, stream>>>(indptr, bsums, fill, srcs);
    k_fill_edges<<<nb_e8, 256, 0, stream>>>(ei, fill, srcs);

    int nb_g = (N_NODES + BM - 1) / BM;    // 391
    int nb_a = (N_NODES + 3) / 4;          // 12500

    k_gemm<<<nb_g, 256, 0, stream>>>(x, W1, xtf, xt16);
    k_attn<<<nb_a, 256, 0, stream>>>(xt16, indptr, srcs, attl1, attr1, b1, h1, fcW, fcb, 0);
    k_gemm<<<nb_g, 256, 0, stream>>>(h1, W2, xtf, xt16);
    k_attn<<<nb_a, 256, 0, stream>>>(xt16, indptr, srcs, attl2, attr2, b2, outp, fcW, fcb, 1);
}

// Round 9
// 326.096 us; speedup vs baseline: 1.1032x; 1.1032x over previous
//
#include <hip/hip_runtime.h>
#include <hip/hip_fp16.h>
#include <math.h>

#define N_NODES 50000
#define N_EDGES 800000
#define ETOT (N_EDGES + N_NODES)
#define F 128
#define SCAN_B 256
#define NSCAN ((N_NODES + SCAN_B - 1) / SCAN_B)   // 196
#define BM 128                                     // gemm rows per block
#define LOG2E 1.44269504088896341f

typedef _Float16 h2 __attribute__((ext_vector_type(2)));

// ---- xor-1 lane sum via DPP quad_perm [1,0,3,2] (VALU pipe) ----
__device__ __forceinline__ float dpp_xor1(float v) {
    int b = __builtin_amdgcn_update_dpp(0, __float_as_int(v), 0xB1, 0xF, 0xF, true);
    return v + __int_as_float(b);
}

// ---------------- CSR build ----------------
// 8 edges per thread: 2x int4 loads + 8 independent atomic chains.

__global__ void k_count(const int* __restrict__ ei, int* __restrict__ counts) {
    int base = (blockIdx.x * 256 + threadIdx.x) * 8;
    if (base < N_EDGES) {
        int4 a = *(const int4*)(ei + N_EDGES + base);
        int4 b = *(const int4*)(ei + N_EDGES + base + 4);
        atomicAdd(&counts[a.x], 1); atomicAdd(&counts[a.y], 1);
        atomicAdd(&counts[a.z], 1); atomicAdd(&counts[a.w], 1);
        atomicAdd(&counts[b.x], 1); atomicAdd(&counts[b.y], 1);
        atomicAdd(&counts[b.z], 1); atomicAdd(&counts[b.w], 1);
    }
}

__global__ void k_scan1(const int* __restrict__ counts, int* __restrict__ indptr,
                        int* __restrict__ bsums) {
    __shared__ int s[SCAN_B];
    int i = blockIdx.x * SCAN_B + threadIdx.x;
    int v = (i < N_NODES) ? (counts[i] + 1) : 0;   // +1 = self-loop
    s[threadIdx.x] = v;
    __syncthreads();
    #pragma unroll
    for (int off = 1; off < SCAN_B; off <<= 1) {
        int t = (threadIdx.x >= off) ? s[threadIdx.x - off] : 0;
        __syncthreads();
        s[threadIdx.x] += t;
        __syncthreads();
    }
    if (i < N_NODES) indptr[i] = s[threadIdx.x] - v;
    if (threadIdx.x == SCAN_B - 1) bsums[blockIdx.x] = s[SCAN_B - 1];
}

__global__ void k_scan2(int* __restrict__ bsums) {
    __shared__ int s[SCAN_B];
    int v = (threadIdx.x < NSCAN) ? bsums[threadIdx.x] : 0;
    s[threadIdx.x] = v;
    __syncthreads();
    #pragma unroll
    for (int off = 1; off < SCAN_B; off <<= 1) {
        int t = (threadIdx.x >= off) ? s[threadIdx.x - off] : 0;
        __syncthreads();
        s[threadIdx.x] += t;
        __syncthreads();
    }
    if (threadIdx.x < NSCAN) bsums[threadIdx.x] = s[threadIdx.x] - v;
}

__global__ void k_scan3_fill(int* __restrict__ indptr, const int* __restrict__ bsums,
                             int* __restrict__ fill, int* __restrict__ srcs) {
    int i = blockIdx.x * SCAN_B + threadIdx.x;
    if (i < N_NODES) {
        int p = indptr[i] + bsums[blockIdx.x];
        indptr[i] = p;
        fill[i] = p + 1;
        srcs[p] = i;            // self-loop edge first
    }
    if (i == 0) indptr[N_NODES] = ETOT;
}

__global__ void k_fill_edges(const int* __restrict__ ei, int* __restrict__ fill,
                             int* __restrict__ srcs) {
    int base = (blockIdx.x * 256 + threadIdx.x) * 8;
    if (base < N_EDGES) {
        int4 sa = *(const int4*)(ei + base);
        int4 sb = *(const int4*)(ei + base + 4);
        int4 da = *(const int4*)(ei + N_EDGES + base);
        int4 db = *(const int4*)(ei + N_EDGES + base + 4);
        int p0 = atomicAdd(&fill[da.x], 1);
        int p1 = atomicAdd(&fill[da.y], 1);
        int p2 = atomicAdd(&fill[da.z], 1);
        int p3 = atomicAdd(&fill[da.w], 1);
        int p4 = atomicAdd(&fill[db.x], 1);
        int p5 = atomicAdd(&fill[db.y], 1);
        int p6 = atomicAdd(&fill[db.z], 1);
        int p7 = atomicAdd(&fill[db.w], 1);
        srcs[p0] = sa.x; srcs[p1] = sa.y; srcs[p2] = sa.z; srcs[p3] = sa.w;
        srcs[p4] = sb.x; srcs[p5] = sb.y; srcs[p6] = sb.z; srcs[p7] = sb.w;
    }
}

// ---------------- GEMM: Ch[N,128] fp16 = fp32(A[N,128] @ W[128,128]) ----------------
// Column-split: each block does BM=128 rows x 64 cols; W-half in LDS = 32 KB
// -> 5 blocks/CU (vs 2 at 64 KB). acc 8x4. Only the fp16 copy is stored
// (the fp32 product is never read downstream).

__global__ __launch_bounds__(256) void k_gemm(const float* __restrict__ A,
                                              const float* __restrict__ W,
                                              unsigned char* __restrict__ Ch) {
    __shared__ float Ws[F][64];    // 32 KB: cols ch*64 .. ch*64+63
    int t = threadIdx.x;
    int tile = blockIdx.x >> 1;
    int chf = blockIdx.x & 1;      // column half
    int r0 = tile * BM;

    const float4* W4 = (const float4*)W;
    #pragma unroll
    for (int jj = 0; jj < 8; ++jj) {
        int i = t + jj * 256;              // 0..2047 float4
        int k = i >> 4;
        int c4 = i & 15;
        *(float4*)&Ws[k][c4 * 4] = W4[k * 32 + chf * 16 + c4];
    }
    __syncthreads();

    int cg = t & 15;               // col group: cols cg*4..cg*4+3 (within half)
    int rg = t >> 4;               // row group: rows r0+rg*8..+7
    int rbase = r0 + rg * 8;

    const float4* Ap[8];
    #pragma unroll
    for (int i = 0; i < 8; ++i) {
        int gr = rbase + i;
        if (gr >= N_NODES) gr = N_NODES - 1;
        Ap[i] = (const float4*)A + (size_t)gr * 32;
    }

    float acc[8][4];
    #pragma unroll
    for (int i = 0; i < 8; ++i)
        #pragma unroll
        for (int j = 0; j < 4; ++j) acc[i][j] = 0.f;

    #pragma unroll 2
    for (int kk = 0; kk < 32; ++kk) {
        float4 xr[8];
        #pragma unroll
        for (int i = 0; i < 8; ++i) xr[i] = Ap[i][kk];
        #pragma unroll
        for (int kj = 0; kj < 4; ++kj) {
            int k = kk * 4 + kj;
            float4 wa = *(const float4*)&Ws[k][cg * 4];
            #pragma unroll
            for (int i = 0; i < 8; ++i) {
                float xv = (kj == 0) ? xr[i].x : (kj == 1) ? xr[i].y
                         : (kj == 2) ? xr[i].z : xr[i].w;
                acc[i][0] += xv * wa.x; acc[i][1] += xv * wa.y;
                acc[i][2] += xv * wa.z; acc[i][3] += xv * wa.w;
            }
        }
    }

    int colb = chf * 64 + cg * 4;  // global col base
    #pragma unroll
    for (int i = 0; i < 8; ++i) {
        int row = rbase + i;
        if (row < N_NODES) {
            _Float16 hh[4];
            hh[0] = (_Float16)acc[i][0]; hh[1] = (_Float16)acc[i][1];
            hh[2] = (_Float16)acc[i][2]; hh[3] = (_Float16)acc[i][3];
            *(uint2*)(Ch + (size_t)row * 256 + colb * 2) = *(const uint2*)hh;
        }
    }
}

// ---------------- fused attention + aggregate ----------------
// One wave per node; FOUR 16-lane groups each own one edge per step (round-7
// geometry, known-good at deg~17). Lane sl owns 8 feats (head = sl>>1, xor-1
// DPP completes the head). xi read from the fp16 row (no fp32 xtf pass).
// 2-deep prefetch: next row + next srcs issued before current compute.
// Dots via v_dot2_f32_f16; exp->exp2 (LOG2E folded); no max-tracking
// (alphas O(1) for this data; softmax shift-invariant).

__global__ __launch_bounds__(256) void k_attn(
    const unsigned char* __restrict__ xt16,
    const int* __restrict__ indptr, const int* __restrict__ srcs,
    const float* __restrict__ att_l, const float* __restrict__ att_r,
    const float* __restrict__ bias, float* __restrict__ out,
    const float* __restrict__ fcW, const float* __restrict__ fcb, int mode) {

    int wid = threadIdx.x >> 6;
    int lane = threadIdx.x & 63;
    int node = blockIdx.x * 4 + wid;
    if (node >= N_NODES) return;
    int sub = lane >> 4;       // edge slot 0..3
    int sl  = lane & 15;       // feat group: feats sl*8 .. sl*8+7

    // xi (fp16) for own 8 feats
    uint4 xa = *(const uint4*)(xt16 + (size_t)node * 256 + sl * 16);
    h2 xi_h2[4];
    xi_h2[0] = __builtin_bit_cast(h2, xa.x); xi_h2[1] = __builtin_bit_cast(h2, xa.y);
    xi_h2[2] = __builtin_bit_cast(h2, xa.z); xi_h2[3] = __builtin_bit_cast(h2, xa.w);

    const float4* arp = (const float4*)(att_r + sl * 8);
    const float4* alp = (const float4*)(att_l + sl * 8);
    float4 r0 = arp[0], r1 = arp[1];
    float4 l0 = alp[0], l1 = alp[1];
    float rs = (float)xi_h2[0].x*r0.x + (float)xi_h2[0].y*r0.y
             + (float)xi_h2[1].x*r0.z + (float)xi_h2[1].y*r0.w
             + (float)xi_h2[2].x*r1.x + (float)xi_h2[2].y*r1.y
             + (float)xi_h2[3].x*r1.z + (float)xi_h2[3].y*r1.w;
    float ri = LOG2E * dpp_xor1(rs);          // per-head LOG2E*(a_r.x_i)
    h2 al_h2[4];
    al_h2[0] = h2{(_Float16)(l0.x*LOG2E), (_Float16)(l0.y*LOG2E)};
    al_h2[1] = h2{(_Float16)(l0.z*LOG2E), (_Float16)(l0.w*LOG2E)};
    al_h2[2] = h2{(_Float16)(l1.x*LOG2E), (_Float16)(l1.y*LOG2E)};
    al_h2[3] = h2{(_Float16)(l1.z*LOG2E), (_Float16)(l1.w*LOG2E)};

    float d = 0.f;
    float o[8];
    #pragma unroll
    for (int k = 0; k < 8; ++k) o[k] = 0.f;

    int beg = indptr[node], end = indptr[node + 1];
    int nstep = (end - beg + 3) >> 2;

    // pipeline prologue
    int idx = beg + sub;
    bool v0 = idx < end;
    int j0 = srcs[v0 ? idx : beg];
    uint4 ra0 = *(const uint4*)(xt16 + (size_t)j0 * 256 + sl * 16);
    int idx1 = idx + 4;
    bool v1 = idx1 < end;
    int j1 = srcs[v1 ? idx1 : beg];

    for (int s = 0; s < nstep; ++s) {
        // prefetch next row + next-next srcs (overlap compute below)
        uint4 ra1 = *(const uint4*)(xt16 + (size_t)j1 * 256 + sl * 16);
        int idx2 = idx1 + 4;
        bool v2 = idx2 < end;
        int j2 = srcs[v2 ? idx2 : beg];

        // compute current edge
        h2 xj[4];
        xj[0] = __builtin_bit_cast(h2, ra0.x); xj[1] = __builtin_bit_cast(h2, ra0.y);
        xj[2] = __builtin_bit_cast(h2, ra0.z); xj[3] = __builtin_bit_cast(h2, ra0.w);

        float lg = 0.f, lj = 0.f;
        #pragma unroll
        for (int k = 0; k < 4; ++k) {
            lg = __builtin_amdgcn_fdot2(xi_h2[k], xj[k], lg, false);
            lj = __builtin_amdgcn_fdot2(al_h2[k], xj[k], lj, false);
        }
        lg = dpp_xor1(lg);                       // per-head logit
        lj = dpp_xor1(lj);                       // per-head LOG2E*(a_l.x_j)

        float sg = __builtin_amdgcn_rcpf(1.f + __builtin_amdgcn_exp2f(-lg * LOG2E));
        float a = (lj + ri) * sg;
        a = fmaxf(a, 0.f) + 0.2f * fminf(a, 0.f);  // leaky relu (log2-scaled)
        a = v0 ? a : -1e30f;
        float e = __builtin_amdgcn_exp2f(a);
        d += e;
        #pragma unroll
        for (int k = 0; k < 4; ++k) {
            o[2*k]   += e * (float)xj[k].x;
            o[2*k+1] += e * (float)xj[k].y;
        }

        // rotate pipeline
        ra0 = ra1; v0 = v1; v1 = v2; j1 = j2; idx1 = idx2;
    }

    // combine the four 16-lane groups
    d += __shfl_xor(d, 16);
    d += __shfl_xor(d, 32);
    #pragma unroll
    for (int k = 0; k < 8; ++k) {
        o[k] += __shfl_xor(o[k], 16);
        o[k] += __shfl_xor(o[k], 32);
    }

    float inv = __builtin_amdgcn_rcpf(d + 1e-16f);
    const float4* bbp = (const float4*)(bias + sl * 8);
    float4 b0 = bbp[0], b1 = bbp[1];
    float bb[8] = {b0.x, b0.y, b0.z, b0.w, b1.x, b1.y, b1.z, b1.w};
    float g[8];
    #pragma unroll
    for (int k = 0; k < 8; ++k) {
        float v = o[k] * inv + bb[k];
        g[k] = 0.5f * v * (1.f + erff(v * 0.70710678118654752f));  // exact GELU
    }

    if (mode == 0) {
        if (sub == 0) {
            float4* Co = (float4*)(out + (size_t)node * F + sl * 8);
            Co[0] = make_float4(g[0], g[1], g[2], g[3]);
            Co[1] = make_float4(g[4], g[5], g[6], g[7]);
        }
    } else {
        const float4* fwp = (const float4*)(fcW + sl * 8);
        float4 f0 = fwp[0], f1 = fwp[1];
        float p = g[0]*f0.x + g[1]*f0.y + g[2]*f0.z + g[3]*f0.w
                + g[4]*f1.x + g[5]*f1.y + g[6]*f1.z + g[7]*f1.w;
        p += __shfl_xor(p, 1);
        p += __shfl_xor(p, 2);
        p += __shfl_xor(p, 4);
        p += __shfl_xor(p, 8);
        if (lane == 0) out[node] = p + fcb[0];
    }
}

// ---------------- launch ----------------

extern "C" void kernel_launch(void* const* d_in, const int* in_sizes, int n_in,
                              void* d_out, int out_size, void* d_ws, size_t ws_size,
                              hipStream_t stream) {
    const float* x     = (const float*)d_in[0];
    const float* W1    = (const float*)d_in[1];
    const float* b1    = (const float*)d_in[2];
    const float* attl1 = (const float*)d_in[3];
    const float* attr1 = (const float*)d_in[4];
    const float* W2    = (const float*)d_in[5];
    const float* b2    = (const float*)d_in[6];
    const float* attl2 = (const float*)d_in[7];
    const float* attr2 = (const float*)d_in[8];
    const float* fcW   = (const float*)d_in[9];
    const float* fcb   = (const float*)d_in[10];
    const int*   ei    = (const int*)d_in[11];
    float* outp = (float*)d_out;

    // workspace: h1[N][128] f32, xt16[N][256B], CSR ints
    float* h1  = (float*)d_ws;
    unsigned char* xt16 = (unsigned char*)(h1 + (size_t)N_NODES * F);
    int* indptr = (int*)(xt16 + (size_t)N_NODES * 256);
    int* fill   = indptr + (N_NODES + 1);
    int* srcs   = fill + N_NODES;
    int* bsums  = srcs + ETOT;
    int* counts = fill;   // aliased: counts dead after scan1, fill written in scan3_fill

    int nb_e8 = (N_EDGES / 8 + 255) / 256;   // 391

    hipMemsetAsync(counts, 0, N_NODES * sizeof(int), stream);
    k_count<<<nb_e8, 256, 0, stream>>>(ei, counts);
    k_scan1<<<NSCAN, SCAN_B, 0, stream>>>(counts, indptr, bsums);
    k_scan2<<<1, SCAN_B, 0, stream>>>(bsums);
    k_scan3_fill<<<NSCAN, SCAN_B, 0, stream>>>(indptr, bsums, fill, srcs);
    k_fill_edges<<<nb_e8, 256, 0, stream>>>(ei, fill, srcs);

    int nb_g = ((N_NODES + BM - 1) / BM) * 2;   // 782 (row tiles x 2 col halves)
    int nb_a = (N_NODES + 3) / 4;               // 12500

    k_gemm<<<nb_g, 256, 0, stream>>>(x, W1, xt16);
    k_attn<<<nb_a, 256, 0, stream>>>(xt16, indptr, srcs, attl1, attr1, b1, h1, fcW, fcb, 0);
    k_gemm<<<nb_g, 256, 0, stream>>>(h1, W2, xt16);
    k_attn<<<nb_a, 256, 0, stream>>>(xt16, indptr, srcs, attl2, attr2, b2, outp, fcW, fcb, 1);
}

// Round 11
// 297.301 us; speedup vs baseline: 1.2100x; 1.0969x over previous
//
#include <hip/hip_runtime.h>
#include <hip/hip_fp16.h>
#include <math.h>

#define N_NODES 50000
#define N_EDGES 800000
#define ETOT (N_EDGES + N_NODES)
#define F 128
#define SCAN_B 256
#define NSCAN ((N_NODES + SCAN_B - 1) / SCAN_B)   // 196
#define LOG2E 1.44269504088896341f

typedef _Float16 h2 __attribute__((ext_vector_type(2)));
typedef _Float16 h8 __attribute__((ext_vector_type(8)));
typedef float f4v __attribute__((ext_vector_type(4)));

// ---- xor-1 lane sum via DPP quad_perm [1,0,3,2] (VALU pipe) ----
__device__ __forceinline__ float dpp_xor1(float v) {
    int b = __builtin_amdgcn_update_dpp(0, __float_as_int(v), 0xB1, 0xF, 0xF, true);
    return v + __int_as_float(b);
}

// ---------------- prep: zero counts + x->fp16 + W1/W2 -> fp16 transposed ----------------

__global__ void k_prep(const float* __restrict__ x, const float* __restrict__ W1,
                       const float* __restrict__ W2, _Float16* __restrict__ x16,
                       _Float16* __restrict__ WT1, _Float16* __restrict__ WT2,
                       int* __restrict__ counts) {
    int tid = blockIdx.x * 256 + threadIdx.x;
    if (tid < 16384) {
        int k = tid >> 7, c = tid & 127;
        WT1[c * 128 + k] = (_Float16)W1[tid];          // WT[c][k] = W[k][c]
    } else if (tid < 32768) {
        int j = tid - 16384;
        int k = j >> 7, c = j & 127;
        WT2[c * 128 + k] = (_Float16)W2[j];
    } else if (tid < 832768) {
        int i = tid - 32768;                            // 8 floats per thread
        const float4* xp = (const float4*)x + (size_t)i * 2;
        float4 a = xp[0], b = xp[1];
        _Float16 hh[8] = {(_Float16)a.x, (_Float16)a.y, (_Float16)a.z, (_Float16)a.w,
                          (_Float16)b.x, (_Float16)b.y, (_Float16)b.z, (_Float16)b.w};
        *(uint4*)(x16 + (size_t)i * 8) = *(const uint4*)hh;
    } else if (tid < 832768 + N_NODES) {
        counts[tid - 832768] = 0;
    }
}

// ---------------- CSR build (8 edges/thread, independent atomic chains) ----------------

__global__ void k_count(const int* __restrict__ ei, int* __restrict__ counts) {
    int base = (blockIdx.x * 256 + threadIdx.x) * 8;
    if (base < N_EDGES) {
        int4 a = *(const int4*)(ei + N_EDGES + base);
        int4 b = *(const int4*)(ei + N_EDGES + base + 4);
        atomicAdd(&counts[a.x], 1); atomicAdd(&counts[a.y], 1);
        atomicAdd(&counts[a.z], 1); atomicAdd(&counts[a.w], 1);
        atomicAdd(&counts[b.x], 1); atomicAdd(&counts[b.y], 1);
        atomicAdd(&counts[b.z], 1); atomicAdd(&counts[b.w], 1);
    }
}

__global__ void k_scan1(const int* __restrict__ counts, int* __restrict__ indptr,
                        int* __restrict__ bsums) {
    __shared__ int s[SCAN_B];
    int i = blockIdx.x * SCAN_B + threadIdx.x;
    int v = (i < N_NODES) ? (counts[i] + 1) : 0;   // +1 = self-loop
    s[threadIdx.x] = v;
    __syncthreads();
    #pragma unroll
    for (int off = 1; off < SCAN_B; off <<= 1) {
        int t = (threadIdx.x >= off) ? s[threadIdx.x - off] : 0;
        __syncthreads();
        s[threadIdx.x] += t;
        __syncthreads();
    }
    if (i < N_NODES) indptr[i] = s[threadIdx.x] - v;
    if (threadIdx.x == SCAN_B - 1) bsums[blockIdx.x] = s[SCAN_B - 1];
}

__global__ void k_scan2(int* __restrict__ bsums) {
    __shared__ int s[SCAN_B];
    int v = (threadIdx.x < NSCAN) ? bsums[threadIdx.x] : 0;
    s[threadIdx.x] = v;
    __syncthreads();
    #pragma unroll
    for (int off = 1; off < SCAN_B; off <<= 1) {
        int t = (threadIdx.x >= off) ? s[threadIdx.x - off] : 0;
        __syncthreads();
        s[threadIdx.x] += t;
        __syncthreads();
    }
    if (threadIdx.x < NSCAN) bsums[threadIdx.x] = s[threadIdx.x] - v;
}

__global__ void k_scan3_fill(int* __restrict__ indptr, const int* __restrict__ bsums,
                             int* __restrict__ fill, int* __restrict__ srcs) {
    int i = blockIdx.x * SCAN_B + threadIdx.x;
    if (i < N_NODES) {
        int p = indptr[i] + bsums[blockIdx.x];
        indptr[i] = p;
        fill[i] = p + 1;
        srcs[p] = i;            // self-loop edge first
    }
    if (i == 0) indptr[N_NODES] = ETOT;
}

__global__ void k_fill_edges(const int* __restrict__ ei, int* __restrict__ fill,
                             int* __restrict__ srcs) {
    int base = (blockIdx.x * 256 + threadIdx.x) * 8;
    if (base < N_EDGES) {
        int4 sa = *(const int4*)(ei + base);
        int4 sb = *(const int4*)(ei + base + 4);
        int4 da = *(const int4*)(ei + N_EDGES + base);
        int4 db = *(const int4*)(ei + N_EDGES + base + 4);
        int p0 = atomicAdd(&fill[da.x], 1);
        int p1 = atomicAdd(&fill[da.y], 1);
        int p2 = atomicAdd(&fill[da.z], 1);
        int p3 = atomicAdd(&fill[da.w], 1);
        int p4 = atomicAdd(&fill[db.x], 1);
        int p5 = atomicAdd(&fill[db.y], 1);
        int p6 = atomicAdd(&fill[db.z], 1);
        int p7 = atomicAdd(&fill[db.w], 1);
        srcs[p0] = sa.x; srcs[p1] = sa.y; srcs[p2] = sa.z; srcs[p3] = sa.w;
        srcs[p4] = sb.x; srcs[p5] = sb.y; srcs[p6] = sb.z; srcs[p7] = sb.w;
    }
}

// ---------------- MFMA GEMM: Ch[N,128] fp16 = fp16(A[N,128] @ W[128,128]) ----------------
// v_mfma_f32_16x16x32_f16, fp32 accumulate. Block = 4 waves x 16 rows = 64 rows,
// all 128 cols. B-frags from LDS-staged transposed W (WT[col][k], +8B pad -> <=2-way).
// A-frag: row = lane&15, k = kc*32 + (lane>>4)*8 + e (16B contiguous per lane).
// C/D:   col = ct*16 + (lane&15), row = (lane>>4)*4 + reg.

__global__ __launch_bounds__(256) void k_gemm(const _Float16* __restrict__ Ah,
                                              const _Float16* __restrict__ WT,
                                              _Float16* __restrict__ Ch) {
    __shared__ _Float16 Wl[128][132];   // 33.8 KB, padded
    int t = threadIdx.x;

    const uint4* WT4 = (const uint4*)WT;
    #pragma unroll
    for (int jj = 0; jj < 8; ++jj) {
        int i = t + jj * 256;           // 0..2047 x 16B
        int c = i >> 4;
        int k8 = i & 15;
        *(uint4*)&Wl[c][k8 * 8] = WT4[i];
    }
    __syncthreads();

    int wid = t >> 6, lane = t & 63;
    int rbase = blockIdx.x * 64 + wid * 16;
    int rA = rbase + (lane & 15);
    if (rA >= N_NODES) rA = N_NODES - 1;
    int koff = (lane >> 4) * 8;

    const _Float16* Ar = Ah + (size_t)rA * 128;
    h8 af[4];
    #pragma unroll
    for (int kc = 0; kc < 4; ++kc)
        af[kc] = *(const h8*)(Ar + kc * 32 + koff);

    f4v acc[8];
    #pragma unroll
    for (int ct = 0; ct < 8; ++ct) acc[ct] = f4v{0.f, 0.f, 0.f, 0.f};

    int colb = lane & 15;
    #pragma unroll
    for (int ct = 0; ct < 8; ++ct) {
        const _Float16* wrow = &Wl[ct * 16 + colb][koff];
        #pragma unroll
        for (int kc = 0; kc < 4; ++kc) {
            h8 bf = *(const h8*)(wrow + kc * 32);
            acc[ct] = __builtin_amdgcn_mfma_f32_16x16x32_f16(af[kc], bf, acc[ct], 0, 0, 0);
        }
    }

    int rout = rbase + (lane >> 4) * 4;
    #pragma unroll
    for (int r = 0; r < 4; ++r) {
        int row = rout + r;
        if (row < N_NODES) {
            _Float16* Crow = Ch + (size_t)row * 128;
            #pragma unroll
            for (int ct = 0; ct < 8; ++ct)
                Crow[ct * 16 + colb] = (_Float16)acc[ct][r];
        }
    }
}

// ---------------- fused attention + aggregate ----------------
// One wave per node; four 16-lane groups each own one edge per step.
// Lane sl owns 8 feats (head = sl>>1, xor-1 DPP completes the head).
// 2-deep prefetch; fdot2 dots; exp->exp2 (LOG2E folded); no max-tracking.
// mode 0: write fp16 row (feeds MFMA gemm2). mode 1: fc reduce -> fp32 out.

__global__ __launch_bounds__(256) void k_attn(
    const unsigned char* __restrict__ xt16,
    const int* __restrict__ indptr, const int* __restrict__ srcs,
    const float* __restrict__ att_l, const float* __restrict__ att_r,
    const float* __restrict__ bias, float* __restrict__ out,
    _Float16* __restrict__ outh,
    const float* __restrict__ fcW, const float* __restrict__ fcb, int mode) {

    int wid = threadIdx.x >> 6;
    int lane = threadIdx.x & 63;
    int node = blockIdx.x * 4 + wid;
    if (node >= N_NODES) return;
    int sub = lane >> 4;       // edge slot 0..3
    int sl  = lane & 15;       // feat group: feats sl*8 .. sl*8+7

    uint4 xa = *(const uint4*)(xt16 + (size_t)node * 256 + sl * 16);
    h2 xi_h2[4];
    xi_h2[0] = __builtin_bit_cast(h2, xa.x); xi_h2[1] = __builtin_bit_cast(h2, xa.y);
    xi_h2[2] = __builtin_bit_cast(h2, xa.z); xi_h2[3] = __builtin_bit_cast(h2, xa.w);

    const float4* arp = (const float4*)(att_r + sl * 8);
    const float4* alp = (const float4*)(att_l + sl * 8);
    float4 r0 = arp[0], r1 = arp[1];
    float4 l0 = alp[0], l1 = alp[1];
    float rs = (float)xi_h2[0].x*r0.x + (float)xi_h2[0].y*r0.y
             + (float)xi_h2[1].x*r0.z + (float)xi_h2[1].y*r0.w
             + (float)xi_h2[2].x*r1.x + (float)xi_h2[2].y*r1.y
             + (float)xi_h2[3].x*r1.z + (float)xi_h2[3].y*r1.w;
    float ri = LOG2E * dpp_xor1(rs);          // per-head LOG2E*(a_r.x_i)
    h2 al_h2[4];
    al_h2[0] = h2{(_Float16)(l0.x*LOG2E), (_Float16)(l0.y*LOG2E)};
    al_h2[1] = h2{(_Float16)(l0.z*LOG2E), (_Float16)(l0.w*LOG2E)};
    al_h2[2] = h2{(_Float16)(l1.x*LOG2E), (_Float16)(l1.y*LOG2E)};
    al_h2[3] = h2{(_Float16)(l1.z*LOG2E), (_Float16)(l1.w*LOG2E)};

    float d = 0.f;
    float o[8];
    #pragma unroll
    for (int k = 0; k < 8; ++k) o[k] = 0.f;

    int beg = indptr[node], end = indptr[node + 1];
    int nstep = (end - beg + 3) >> 2;

    int idx = beg + sub;
    bool v0 = idx < end;
    int j0 = srcs[v0 ? idx : beg];
    uint4 ra0 = *(const uint4*)(xt16 + (size_t)j0 * 256 + sl * 16);
    int idx1 = idx + 4;
    bool v1 = idx1 < end;
    int j1 = srcs[v1 ? idx1 : beg];

    for (int s = 0; s < nstep; ++s) {
        uint4 ra1 = *(const uint4*)(xt16 + (size_t)j1 * 256 + sl * 16);
        int idx2 = idx1 + 4;
        bool v2 = idx2 < end;
        int j2 = srcs[v2 ? idx2 : beg];

        h2 xj[4];
        xj[0] = __builtin_bit_cast(h2, ra0.x); xj[1] = __builtin_bit_cast(h2, ra0.y);
        xj[2] = __builtin_bit_cast(h2, ra0.z); xj[3] = __builtin_bit_cast(h2, ra0.w);

        float lg = 0.f, lj = 0.f;
        #pragma unroll
        for (int k = 0; k < 4; ++k) {
            lg = __builtin_amdgcn_fdot2(xi_h2[k], xj[k], lg, false);
            lj = __builtin_amdgcn_fdot2(al_h2[k], xj[k], lj, false);
        }
        lg = dpp_xor1(lg);                       // per-head logit
        lj = dpp_xor1(lj);                       // per-head LOG2E*(a_l.x_j)

        float sg = __builtin_amdgcn_rcpf(1.f + __builtin_amdgcn_exp2f(-lg * LOG2E));
        float a = (lj + ri) * sg;
        a = fmaxf(a, 0.f) + 0.2f * fminf(a, 0.f);  // leaky relu (log2-scaled)
        a = v0 ? a : -1e30f;
        float e = __builtin_amdgcn_exp2f(a);
        d += e;
        #pragma unroll
        for (int k = 0; k < 4; ++k) {
            o[2*k]   += e * (float)xj[k].x;
            o[2*k+1] += e * (float)xj[k].y;
        }

        ra0 = ra1; v0 = v1; v1 = v2; j1 = j2; idx1 = idx2;
    }

    d += __shfl_xor(d, 16);
    d += __shfl_xor(d, 32);
    #pragma unroll
    for (int k = 0; k < 8; ++k) {
        o[k] += __shfl_xor(o[k], 16);
        o[k] += __shfl_xor(o[k], 32);
    }

    float inv = __builtin_amdgcn_rcpf(d + 1e-16f);
    const float4* bbp = (const float4*)(bias + sl * 8);
    float4 b0 = bbp[0], b1 = bbp[1];
    float bb[8] = {b0.x, b0.y, b0.z, b0.w, b1.x, b1.y, b1.z, b1.w};
    float g[8];
    #pragma unroll
    for (int k = 0; k < 8; ++k) {
        float v = o[k] * inv + bb[k];
        g[k] = 0.5f * v * (1.f + erff(v * 0.70710678118654752f));  // exact GELU
    }

    if (mode == 0) {
        if (sub == 0) {
            _Float16 hh[8];
            #pragma unroll
            for (int k = 0; k < 8; ++k) hh[k] = (_Float16)g[k];
            *(uint4*)(outh + (size_t)node * 128 + sl * 8) = *(const uint4*)hh;
        }
    } else {
        const float4* fwp = (const float4*)(fcW + sl * 8);
        float4 f0 = fwp[0], f1 = fwp[1];
        float p = g[0]*f0.x + g[1]*f0.y + g[2]*f0.z + g[3]*f0.w
                + g[4]*f1.x + g[5]*f1.y + g[6]*f1.z + g[7]*f1.w;
        p += __shfl_xor(p, 1);
        p += __shfl_xor(p, 2);
        p += __shfl_xor(p, 4);
        p += __shfl_xor(p, 8);
        if (lane == 0) out[node] = p + fcb[0];
    }
}

// ---------------- launch ----------------

extern "C" void kernel_launch(void* const* d_in, const int* in_sizes, int n_in,
                              void* d_out, int out_size, void* d_ws, size_t ws_size,
                              hipStream_t stream) {
    const float* x     = (const float*)d_in[0];
    const float* W1    = (const float*)d_in[1];
    const float* b1    = (const float*)d_in[2];
    const float* attl1 = (const float*)d_in[3];
    const float* attr1 = (const float*)d_in[4];
    const float* W2    = (const float*)d_in[5];
    const float* b2    = (const float*)d_in[6];
    const float* attl2 = (const float*)d_in[7];
    const float* attr2 = (const float*)d_in[8];
    const float* fcW   = (const float*)d_in[9];
    const float* fcb   = (const float*)d_in[10];
    const int*   ei    = (const int*)d_in[11];
    float* outp = (float*)d_out;

    // workspace: x16, h16, xt16 (fp16 [N][128] each), WT1, WT2, CSR ints (~39 MB)
    _Float16* x16  = (_Float16*)d_ws;
    _Float16* h16  = x16 + (size_t)N_NODES * F;
    _Float16* xt16 = h16 + (size_t)N_NODES * F;
    _Float16* WT1  = xt16 + (size_t)N_NODES * F;
    _Float16* WT2  = WT1 + F * F;
    int* indptr = (int*)(WT2 + F * F);
    int* fill   = indptr + (N_NODES + 1);
    int* srcs   = fill + N_NODES;
    int* bsums  = srcs + ETOT;
    int* counts = fill;   // aliased: counts dead after scan1, fill written in scan3_fill

    int nb_e8 = (N_EDGES / 8 + 255) / 256;   // 391
    int nb_p  = (832768 + N_NODES + 255) / 256;

    k_prep<<<nb_p, 256, 0, stream>>>(x, W1, W2, x16, WT1, WT2, counts);
    k_count<<<nb_e8, 256, 0, stream>>>(ei, counts);
    k_scan1<<<NSCAN, SCAN_B, 0, stream>>>(counts, indptr, bsums);
    k_scan2<<<1, SCAN_B, 0, stream>>>(bsums);
    k_scan3_fill<<<NSCAN, SCAN_B, 0, stream>>>(indptr, bsums, fill, srcs);
    k_fill_edges<<<nb_e8, 256, 0, stream>>>(ei, fill, srcs);

    int nb_g = (N_NODES + 63) / 64;    // 782
    int nb_a = (N_NODES + 3) / 4;      // 12500

    k_gemm<<<nb_g, 256, 0, stream>>>(x16, WT1, xt16);
    k_attn<<<nb_a, 256, 0, stream>>>((const unsigned char*)xt16, indptr, srcs,
                                     attl1, attr1, b1, outp, h16, fcW, fcb, 0);
    k_gemm<<<nb_g, 256, 0, stream>>>(h16, WT2, xt16);
    k_attn<<<nb_a, 256, 0, stream>>>((const unsigned char*)xt16, indptr, srcs,
                                     attl2, attr2, b2, outp, h16, fcW, fcb, 1);
}

// Round 13
// 264.679 us; speedup vs baseline: 1.3591x; 1.1233x over previous
//
#include <hip/hip_runtime.h>
#include <hip/hip_fp16.h>
#include <math.h>

#define N_NODES 50000
#define N_EDGES 800000
#define ETOT (N_EDGES + N_NODES)
#define F 128
#define SCAN_B 256
#define NSCAN ((N_NODES + SCAN_B - 1) / SCAN_B)   // 196
#define LOG2E 1.44269504088896341f

typedef _Float16 h2 __attribute__((ext_vector_type(2)));
typedef _Float16 h8 __attribute__((ext_vector_type(8)));
typedef float f4v __attribute__((ext_vector_type(4)));

// ---- xor-1 lane sum via DPP quad_perm [1,0,3,2] (VALU pipe) ----
__device__ __forceinline__ float dpp_xor1(float v) {
    int b = __builtin_amdgcn_update_dpp(0, __float_as_int(v), 0xB1, 0xF, 0xF, true);
    return v + __int_as_float(b);
}

// ---------------- prep: zero fill0 + x->fp16 + W1/W2 -> fp16 transposed ----------------

__global__ void k_prep(const float* __restrict__ x, const float* __restrict__ W1,
                       const float* __restrict__ W2, _Float16* __restrict__ x16,
                       _Float16* __restrict__ WT1, _Float16* __restrict__ WT2,
                       int* __restrict__ fill0) {
    int tid = blockIdx.x * 256 + threadIdx.x;
    if (tid < 16384) {
        int k = tid >> 7, c = tid & 127;
        WT1[c * 128 + k] = (_Float16)W1[tid];          // WT[c][k] = W[k][c]
    } else if (tid < 32768) {
        int j = tid - 16384;
        int k = j >> 7, c = j & 127;
        WT2[c * 128 + k] = (_Float16)W2[j];
    } else if (tid < 832768) {
        int i = tid - 32768;                            // 8 floats per thread
        const float4* xp = (const float4*)x + (size_t)i * 2;
        float4 a = xp[0], b = xp[1];
        _Float16 hh[8] = {(_Float16)a.x, (_Float16)a.y, (_Float16)a.z, (_Float16)a.w,
                          (_Float16)b.x, (_Float16)b.y, (_Float16)b.z, (_Float16)b.w};
        *(uint4*)(x16 + (size_t)i * 8) = *(const uint4*)hh;
    } else if (tid < 832768 + N_NODES) {
        fill0[tid - 832768] = 0;
    }
}

// ---------------- CSR build ----------------
// Single atomic pass: pos[e] = rank of edge e among edges with the same dst.
// fill0 ends up holding the per-dst edge count (consumed by scan1).

__global__ void k_pos(const int* __restrict__ ei, int* __restrict__ fill0,
                      int* __restrict__ pos) {
    int base = (blockIdx.x * 256 + threadIdx.x) * 4;
    if (base < N_EDGES) {
        int4 d4 = *(const int4*)(ei + N_EDGES + base);
        int p0 = atomicAdd(&fill0[d4.x], 1);
        int p1 = atomicAdd(&fill0[d4.y], 1);
        int p2 = atomicAdd(&fill0[d4.z], 1);
        int p3 = atomicAdd(&fill0[d4.w], 1);
        *(int4*)(pos + base) = make_int4(p0, p1, p2, p3);
    }
}

__global__ void k_scan1(const int* __restrict__ counts, int* __restrict__ indptr,
                        int* __restrict__ bsums) {
    __shared__ int s[SCAN_B];
    int i = blockIdx.x * SCAN_B + threadIdx.x;
    int v = (i < N_NODES) ? (counts[i] + 1) : 0;   // +1 = self-loop
    s[threadIdx.x] = v;
    __syncthreads();
    #pragma unroll
    for (int off = 1; off < SCAN_B; off <<= 1) {
        int t = (threadIdx.x >= off) ? s[threadIdx.x - off] : 0;
        __syncthreads();
        s[threadIdx.x] += t;
        __syncthreads();
    }
    if (i < N_NODES) indptr[i] = s[threadIdx.x] - v;
    if (threadIdx.x == SCAN_B - 1) bsums[blockIdx.x] = s[SCAN_B - 1];
}

__global__ void k_scan2(int* __restrict__ bsums) {
    __shared__ int s[SCAN_B];
    int v = (threadIdx.x < NSCAN) ? bsums[threadIdx.x] : 0;
    s[threadIdx.x] = v;
    __syncthreads();
    #pragma unroll
    for (int off = 1; off < SCAN_B; off <<= 1) {
        int t = (threadIdx.x >= off) ? s[threadIdx.x - off] : 0;
        __syncthreads();
        s[threadIdx.x] += t;
        __syncthreads();
    }
    if (threadIdx.x < NSCAN) bsums[threadIdx.x] = s[threadIdx.x] - v;
}

__global__ void k_scan3_fill(int* __restrict__ indptr, const int* __restrict__ bsums,
                             int* __restrict__ srcs) {
    int i = blockIdx.x * SCAN_B + threadIdx.x;
    if (i < N_NODES) {
        int p = indptr[i] + bsums[blockIdx.x];
        indptr[i] = p;
        srcs[p] = i;            // self-loop edge first
    }
    if (i == 0) indptr[N_NODES] = ETOT;
}

// pure streaming scatter — no atomics (positions precomputed by k_pos)
__global__ void k_scatter(const int* __restrict__ ei, const int* __restrict__ indptr,
                          const int* __restrict__ pos, int* __restrict__ srcs) {
    int base = (blockIdx.x * 256 + threadIdx.x) * 8;
    if (base < N_EDGES) {
        int4 sa = *(const int4*)(ei + base);
        int4 sb = *(const int4*)(ei + base + 4);
        int4 da = *(const int4*)(ei + N_EDGES + base);
        int4 db = *(const int4*)(ei + N_EDGES + base + 4);
        int4 pa = *(const int4*)(pos + base);
        int4 pb = *(const int4*)(pos + base + 4);
        srcs[indptr[da.x] + 1 + pa.x] = sa.x;
        srcs[indptr[da.y] + 1 + pa.y] = sa.y;
        srcs[indptr[da.z] + 1 + pa.z] = sa.z;
        srcs[indptr[da.w] + 1 + pa.w] = sa.w;
        srcs[indptr[db.x] + 1 + pb.x] = sb.x;
        srcs[indptr[db.y] + 1 + pb.y] = sb.y;
        srcs[indptr[db.z] + 1 + pb.z] = sb.z;
        srcs[indptr[db.w] + 1 + pb.w] = sb.w;
    }
}

// ---------------- MFMA GEMM: Ch[N,128] fp16 = fp16(A[N,128] @ W[128,128]) ----------------
// v_mfma_f32_16x16x32_f16, fp32 accumulate. Block = 4 waves x 16 rows = 64 rows,
// all 128 cols. B-frags from LDS-staged transposed W (WT[col][k], +8B pad -> <=2-way).
// A-frag: row = lane&15, k = kc*32 + (lane>>4)*8 + e. C/D: col = ct*16 + (lane&15),
// row = (lane>>4)*4 + reg.

__global__ __launch_bounds__(256) void k_gemm(const _Float16* __restrict__ Ah,
                                              const _Float16* __restrict__ WT,
                                              _Float16* __restrict__ Ch) {
    __shared__ _Float16 Wl[128][132];   // 33.8 KB, padded
    int t = threadIdx.x;

    const uint4* WT4 = (const uint4*)WT;
    #pragma unroll
    for (int jj = 0; jj < 8; ++jj) {
        int i = t + jj * 256;           // 0..2047 x 16B
        int c = i >> 4;
        int k8 = i & 15;
        *(uint4*)&Wl[c][k8 * 8] = WT4[i];
    }
    __syncthreads();

    int wid = t >> 6, lane = t & 63;
    int rbase = blockIdx.x * 64 + wid * 16;
    int rA = rbase + (lane & 15);
    if (rA >= N_NODES) rA = N_NODES - 1;
    int koff = (lane >> 4) * 8;

    const _Float16* Ar = Ah + (size_t)rA * 128;
    h8 af[4];
    #pragma unroll
    for (int kc = 0; kc < 4; ++kc)
        af[kc] = *(const h8*)(Ar + kc * 32 + koff);

    f4v acc[8];
    #pragma unroll
    for (int ct = 0; ct < 8; ++ct) acc[ct] = f4v{0.f, 0.f, 0.f, 0.f};

    int colb = lane & 15;
    #pragma unroll
    for (int ct = 0; ct < 8; ++ct) {
        const _Float16* wrow = &Wl[ct * 16 + colb][koff];
        #pragma unroll
        for (int kc = 0; kc < 4; ++kc) {
            h8 bf = *(const h8*)(wrow + kc * 32);
            acc[ct] = __builtin_amdgcn_mfma_f32_16x16x32_f16(af[kc], bf, acc[ct], 0, 0, 0);
        }
    }

    int rout = rbase + (lane >> 4) * 4;
    #pragma unroll
    for (int r = 0; r < 4; ++r) {
        int row = rout + r;
        if (row < N_NODES) {
            _Float16* Crow = Ch + (size_t)row * 128;
            #pragma unroll
            for (int ct = 0; ct < 8; ++ct)
                Crow[ct * 16 + colb] = (_Float16)acc[ct][r];
        }
    }
}

// ---------------- fused attention + aggregate ----------------
// One wave per node; four 16-lane groups each own one edge per step.
// Lane sl owns 8 feats (head = sl>>1, xor-1 DPP completes the head).
// 2-deep prefetch; fdot2 dots; exp->exp2 (LOG2E folded); no max-tracking.
// Epilogue: each lane finalizes only its (sub) 2-feat slice -> 2 erff/lane
// instead of 8 (o[] kept in regs via explicit sub-select, not runtime index).
// mode 0: 4B/lane coalesced fp16 store. mode 1: full 64-lane fc reduce.

__global__ __launch_bounds__(256) void k_attn(
    const unsigned char* __restrict__ xt16,
    const int* __restrict__ indptr, const int* __restrict__ srcs,
    const float* __restrict__ att_l, const float* __restrict__ att_r,
    const float* __restrict__ bias, float* __restrict__ out,
    _Float16* __restrict__ outh,
    const float* __restrict__ fcW, const float* __restrict__ fcb, int mode) {

    int wid = threadIdx.x >> 6;
    int lane = threadIdx.x & 63;
    int node = blockIdx.x * 4 + wid;
    if (node >= N_NODES) return;
    int sub = lane >> 4;       // edge slot 0..3
    int sl  = lane & 15;       // feat group: feats sl*8 .. sl*8+7

    uint4 xa = *(const uint4*)(xt16 + (size_t)node * 256 + sl * 16);
    h2 xi_h2[4];
    xi_h2[0] = __builtin_bit_cast(h2, xa.x); xi_h2[1] = __builtin_bit_cast(h2, xa.y);
    xi_h2[2] = __builtin_bit_cast(h2, xa.z); xi_h2[3] = __builtin_bit_cast(h2, xa.w);

    const float4* arp = (const float4*)(att_r + sl * 8);
    const float4* alp = (const float4*)(att_l + sl * 8);
    float4 r0 = arp[0], r1 = arp[1];
    float4 l0 = alp[0], l1 = alp[1];
    float rs = (float)xi_h2[0].x*r0.x + (float)xi_h2[0].y*r0.y
             + (float)xi_h2[1].x*r0.z + (float)xi_h2[1].y*r0.w
             + (float)xi_h2[2].x*r1.x + (float)xi_h2[2].y*r1.y
             + (float)xi_h2[3].x*r1.z + (float)xi_h2[3].y*r1.w;
    float ri = LOG2E * dpp_xor1(rs);          // per-head LOG2E*(a_r.x_i)
    h2 al_h2[4];
    al_h2[0] = h2{(_Float16)(l0.x*LOG2E), (_Float16)(l0.y*LOG2E)};
    al_h2[1] = h2{(_Float16)(l0.z*LOG2E), (_Float16)(l0.w*LOG2E)};
    al_h2[2] = h2{(_Float16)(l1.x*LOG2E), (_Float16)(l1.y*LOG2E)};
    al_h2[3] = h2{(_Float16)(l1.z*LOG2E), (_Float16)(l1.w*LOG2E)};

    float d = 0.f;
    float o[8];
    #pragma unroll
    for (int k = 0; k < 8; ++k) o[k] = 0.f;

    int beg = indptr[node], end = indptr[node + 1];
    int nstep = (end - beg + 3) >> 2;

    int idx = beg + sub;
    bool v0 = idx < end;
    int j0 = srcs[v0 ? idx : beg];
    uint4 ra0 = *(const uint4*)(xt16 + (size_t)j0 * 256 + sl * 16);
    int idx1 = idx + 4;
    bool v1 = idx1 < end;
    int j1 = srcs[v1 ? idx1 : beg];

    for (int s = 0; s < nstep; ++s) {
        uint4 ra1 = *(const uint4*)(xt16 + (size_t)j1 * 256 + sl * 16);
        int idx2 = idx1 + 4;
        bool v2 = idx2 < end;
        int j2 = srcs[v2 ? idx2 : beg];

        h2 xj[4];
        xj[0] = __builtin_bit_cast(h2, ra0.x); xj[1] = __builtin_bit_cast(h2, ra0.y);
        xj[2] = __builtin_bit_cast(h2, ra0.z); xj[3] = __builtin_bit_cast(h2, ra0.w);

        float lg = 0.f, lj = 0.f;
        #pragma unroll
        for (int k = 0; k < 4; ++k) {
            lg = __builtin_amdgcn_fdot2(xi_h2[k], xj[k], lg, false);
            lj = __builtin_amdgcn_fdot2(al_h2[k], xj[k], lj, false);
        }
        lg = dpp_xor1(lg);                       // per-head logit
        lj = dpp_xor1(lj);                       // per-head LOG2E*(a_l.x_j)

        float sg = __builtin_amdgcn_rcpf(1.f + __builtin_amdgcn_exp2f(-lg * LOG2E));
        float a = (lj + ri) * sg;
        a = fmaxf(a, 0.f) + 0.2f * fminf(a, 0.f);  // leaky relu (log2-scaled)
        a = v0 ? a : -1e30f;
        float e = __builtin_amdgcn_exp2f(a);
        d += e;
        #pragma unroll
        for (int k = 0; k < 4; ++k) {
            o[2*k]   += e * (float)xj[k].x;
            o[2*k+1] += e * (float)xj[k].y;
        }

        ra0 = ra1; v0 = v1; v1 = v2; j1 = j2; idx1 = idx2;
    }

    d += __shfl_xor(d, 16);
    d += __shfl_xor(d, 32);
    #pragma unroll
    for (int k = 0; k < 8; ++k) {
        o[k] += __shfl_xor(o[k], 16);
        o[k] += __shfl_xor(o[k], 32);
    }

    float inv = __builtin_amdgcn_rcpf(d + 1e-16f);
    // lane finalizes feats sl*8 + sub*2 + {0,1}; explicit select keeps o in regs
    float oa, ob;
    if (sub == 0)      { oa = o[0]; ob = o[1]; }
    else if (sub == 1) { oa = o[2]; ob = o[3]; }
    else if (sub == 2) { oa = o[4]; ob = o[5]; }
    else               { oa = o[6]; ob = o[7]; }
    float2 bb2 = ((const float2*)bias)[sl * 4 + sub];
    float va = oa * inv + bb2.x;
    float vb = ob * inv + bb2.y;
    float ga = 0.5f * va * (1.f + erff(va * 0.70710678118654752f));
    float gb = 0.5f * vb * (1.f + erff(vb * 0.70710678118654752f));

    if (mode == 0) {
        h2 hh = h2{(_Float16)ga, (_Float16)gb};
        *(h2*)(outh + (size_t)node * 128 + sl * 8 + sub * 2) = hh;
    } else {
        float2 fw2 = ((const float2*)fcW)[sl * 4 + sub];
        float p = ga * fw2.x + gb * fw2.y;
        p += __shfl_xor(p, 1);
        p += __shfl_xor(p, 2);
        p += __shfl_xor(p, 4);
        p += __shfl_xor(p, 8);
        p += __shfl_xor(p, 16);
        p += __shfl_xor(p, 32);
        if (lane == 0) out[node] = p + fcb[0];
    }
}

// ---------------- launch ----------------

extern "C" void kernel_launch(void* const* d_in, const int* in_sizes, int n_in,
                              void* d_out, int out_size, void* d_ws, size_t ws_size,
                              hipStream_t stream) {
    const float* x     = (const float*)d_in[0];
    const float* W1    = (const float*)d_in[1];
    const float* b1    = (const float*)d_in[2];
    const float* attl1 = (const float*)d_in[3];
    const float* attr1 = (const float*)d_in[4];
    const float* W2    = (const float*)d_in[5];
    const float* b2    = (const float*)d_in[6];
    const float* attl2 = (const float*)d_in[7];
    const float* attr2 = (const float*)d_in[8];
    const float* fcW   = (const float*)d_in[9];
    const float* fcb   = (const float*)d_in[10];
    const int*   ei    = (const int*)d_in[11];
    float* outp = (float*)d_out;

    // workspace: x16, h16, xt16 (fp16 [N][128]), WT1, WT2, CSR ints + pos (~46 MB)
    _Float16* x16  = (_Float16*)d_ws;
    _Float16* h16  = x16 + (size_t)N_NODES * F;
    _Float16* xt16 = h16 + (size_t)N_NODES * F;
    _Float16* WT1  = xt16 + (size_t)N_NODES * F;
    _Float16* WT2  = WT1 + F * F;
    int* indptr = (int*)(WT2 + F * F);
    int* fill0  = indptr + (N_NODES + 1);
    int* srcs   = fill0 + N_NODES;
    int* bsums  = srcs + ETOT;
    int* pos    = bsums + NSCAN;

    int nb_e4 = (N_EDGES / 4 + 255) / 256;   // 782
    int nb_e8 = (N_EDGES / 8 + 255) / 256;   // 391
    int nb_p  = (832768 + N_NODES + 255) / 256;

    k_prep<<<nb_p, 256, 0, stream>>>(x, W1, W2, x16, WT1, WT2, fill0);
    k_pos<<<nb_e4, 256, 0, stream>>>(ei, fill0, pos);
    k_scan1<<<NSCAN, SCAN_B, 0, stream>>>(fill0, indptr, bsums);
    k_scan2<<<1, SCAN_B, 0, stream>>>(bsums);
    k_scan3_fill<<<NSCAN, SCAN_B, 0, stream>>>(indptr, bsums, srcs);
    k_scatter<<<nb_e8, 256, 0, stream>>>(ei, indptr, pos, srcs);

    int nb_g = (N_NODES + 63) / 64;    // 782
    int nb_a = (N_NODES + 3) / 4;      // 12500

    k_gemm<<<nb_g, 256, 0, stream>>>(x16, WT1, xt16);
    k_attn<<<nb_a, 256, 0, stream>>>((const unsigned char*)xt16, indptr, srcs,
                                     attl1, attr1, b1, outp, h16, fcW, fcb, 0);
    k_gemm<<<nb_g, 256, 0, stream>>>(h16, WT2, xt16);
    k_attn<<<nb_a, 256, 0, stream>>>((const unsigned char*)xt16, indptr, srcs,
                                     attl2, attr2, b2, outp, h16, fcW, fcb, 1);
}